// Round 1
// baseline (329.567 us; speedup 1.0000x reference)
//
#include <hip/hip_runtime.h>
#include <math.h>

// Problem dims
#define AA 256
#define HH 1024
#define CC 1024
#define NN 8192
#define MM 4096

// ws layout (float offsets). Total 26628 floats (~107 KB).
#define WS_G      0
#define WS_GAMMA  1
#define WS_SR     2
#define WS_SW     3
#define GI_OFF    4
#define GH_OFF    (GI_OFF + 3*CC)     // 3076
#define TR_OFF    (GH_OFF + 3*CC)     // 6148
#define TW_OFF    (TR_OFF + NN)       // 14340
#define ACC_OFF   (TW_OFF + NN)       // 22532

__device__ __forceinline__ float wave_reduce(float v) {
    #pragma unroll
    for (int o = 32; o > 0; o >>= 1) v += __shfl_down(v, o);
    return v;
}

// Kernel 1: gi[row] = dot(x, W_ih[row]) + b_ih, gh[row] = dot(h_prev, W_hh[row]) + b_hh
// x = concat(action[256], hidden[1024]). One block per row (3072 rows).
// Side work: zero the read_vector accumulator + S_r/S_w (ws is 0xAA-poisoned each launch).
__global__ __launch_bounds__(256) void k_gru_gates(
    const float* __restrict__ action, const float* __restrict__ hidden,
    const float* __restrict__ W_ih, const float* __restrict__ W_hh,
    const float* __restrict__ b_ih, const float* __restrict__ b_hh,
    const float* __restrict__ hprev, float* __restrict__ ws)
{
    const int row = blockIdx.x;
    const int t = threadIdx.x;

    if (row < 16) ws[ACC_OFF + row * 256 + t] = 0.0f;     // 16*256 = 4096 acc slots
    if (row == 16 && t < 2) ws[WS_SR + t] = 0.0f;

    const float4* __restrict__ Wih4 = (const float4*)W_ih + (size_t)row * 320; // 1280/4
    const float4* __restrict__ Whh4 = (const float4*)W_hh + (size_t)row * 256; // 1024/4
    const float4* __restrict__ act4 = (const float4*)action;  // 64 float4
    const float4* __restrict__ hid4 = (const float4*)hidden;  // 256 float4
    const float4* __restrict__ hp4  = (const float4*)hprev;   // 256 float4

    float si, sh;
    {
        float4 w = Wih4[t];
        float4 x = (t < 64) ? act4[t] : hid4[t - 64];
        si = w.x * x.x + w.y * x.y + w.z * x.z + w.w * x.w;
        if (t < 64) {  // second pass: f4 idx 256..319 -> x elems 1024..1279 -> hidden 768..1023
            float4 w2 = Wih4[256 + t];
            float4 x2 = hid4[192 + t];
            si += w2.x * x2.x + w2.y * x2.y + w2.z * x2.z + w2.w * x2.w;
        }
    }
    {
        float4 w = Whh4[t];
        float4 x = hp4[t];
        sh = w.x * x.x + w.y * x.y + w.z * x.z + w.w * x.w;
    }
    si = wave_reduce(si);
    sh = wave_reduce(sh);
    __shared__ float red[8];
    const int wid = t >> 6;
    if ((t & 63) == 0) { red[wid] = si; red[4 + wid] = sh; }
    __syncthreads();
    if (t == 0) {
        ws[GI_OFF + row] = red[0] + red[1] + red[2] + red[3] + b_ih[row];
        ws[GH_OFF + row] = red[4] + red[5] + red[6] + red[7] + b_hh[row];
    }
}

// Kernel 2 (1 block, 1024 threads): GRU combine -> h; write hidden output;
// reduce g = sigmoid(h.W_gate + b), gamma = softplus(h.W_gamma + b).
__global__ __launch_bounds__(1024) void k_gru_combine(
    const float* __restrict__ hprev,
    const float* __restrict__ W_gate, const float* __restrict__ b_gate,
    const float* __restrict__ W_gamma, const float* __restrict__ b_gamma,
    float* __restrict__ ws, float* __restrict__ d_out)
{
    const int c = threadIdx.x;
    const float* gi = ws + GI_OFF;
    const float* gh = ws + GH_OFF;
    const float r = 1.0f / (1.0f + expf(-(gi[c] + gh[c])));
    const float z = 1.0f / (1.0f + expf(-(gi[CC + c] + gh[CC + c])));
    const float n = tanhf(gi[2 * CC + c] + r * gh[2 * CC + c]);
    const float h = (1.0f - z) * n + z * hprev[c];
    d_out[MM + 2 * NN + c] = h;   // new_controller_hidden section

    float vg = h * W_gate[c];
    float vm = h * W_gamma[c];
    vg = wave_reduce(vg);
    vm = wave_reduce(vm);
    __shared__ float rg[16], rm[16];
    const int wid = c >> 6;
    if ((c & 63) == 0) { rg[wid] = vg; rm[wid] = vm; }
    __syncthreads();
    if (c == 0) {
        float sg = 0.0f, sm = 0.0f;
        #pragma unroll
        for (int i = 0; i < 16; ++i) { sg += rg[i]; sm += rm[i]; }
        sg += b_gate[0];
        sm += b_gamma[0];
        ws[WS_G] = 1.0f / (1.0f + expf(-sg));
        ws[WS_GAMMA] = (sm > 20.0f) ? sm : log1pf(expf(sm));
    }
}

// Kernel 3: cosine-sim weights are identically 1.0 (softmax over size-1 axis),
// circular-conv scalar cancels in sharpen. t_i = (g + (1-g)*prev_i)^gamma; sums S_r/S_w.
__global__ __launch_bounds__(256) void k_weights(
    const float* __restrict__ prev_r, const float* __restrict__ prev_w,
    float* __restrict__ ws)
{
    const int i = blockIdx.x * 256 + threadIdx.x;  // grid 32 -> 8192
    const float g = ws[WS_G];
    const float gamma = ws[WS_GAMMA];
    float tr = powf(g + (1.0f - g) * prev_r[i], gamma);
    float tw = powf(g + (1.0f - g) * prev_w[i], gamma);
    ws[TR_OFF + i] = tr;
    ws[TW_OFF + i] = tw;
    tr = wave_reduce(tr);
    tw = wave_reduce(tw);
    __shared__ float rr[4], rw[4];
    const int wid = threadIdx.x >> 6;
    if ((threadIdx.x & 63) == 0) { rr[wid] = tr; rw[wid] = tw; }
    __syncthreads();
    if (threadIdx.x == 0) {
        atomicAdd(&ws[WS_SR], rr[0] + rr[1] + rr[2] + rr[3]);
        atomicAdd(&ws[WS_SW], rw[0] + rw[1] + rw[2] + rw[3]);
    }
}

// Kernel 4: acc[m] += sum_{rows in chunk} t_r[row] * memory[row, m].  The 128 MB pass.
// grid (4, 256): block covers 256 float4-cols x 32 rows; fully coalesced 16B/lane loads.
__global__ __launch_bounds__(256) void k_readvec(
    const float* __restrict__ memory, float* __restrict__ ws)
{
    __shared__ float tch[32];
    const int t = threadIdx.x;
    const int row0 = blockIdx.y * 32;
    if (t < 32) tch[t] = ws[TR_OFF + row0 + t];
    __syncthreads();
    const int c4 = blockIdx.x * 256 + t;  // float4 column, 0..1023
    const float4* __restrict__ mem4 = (const float4*)memory;
    float ax = 0.0f, ay = 0.0f, az = 0.0f, aw = 0.0f;
    #pragma unroll 4
    for (int r = 0; r < 32; ++r) {
        float4 m = mem4[(size_t)(row0 + r) * 1024 + c4];
        const float w = tch[r];
        ax += w * m.x; ay += w * m.y; az += w * m.z; aw += w * m.w;
    }
    float* acc = ws + ACC_OFF;
    atomicAdd(&acc[c4 * 4 + 0], ax);
    atomicAdd(&acc[c4 * 4 + 1], ay);
    atomicAdd(&acc[c4 * 4 + 2], az);
    atomicAdd(&acc[c4 * 4 + 3], aw);
}

// Kernel 5: finalize outputs: read_vector = acc/S_r, weights = t/S.
__global__ __launch_bounds__(256) void k_finalize(
    const float* __restrict__ ws, float* __restrict__ d_out)
{
    const int idx = blockIdx.x * 256 + threadIdx.x;  // grid 80 -> 20480
    const float Sr = ws[WS_SR];
    const float Sw = ws[WS_SW];
    if (idx < MM)            d_out[idx] = ws[ACC_OFF + idx] / Sr;
    else if (idx < MM + NN)  d_out[idx] = ws[TR_OFF + idx - MM] / Sr;
    else                     d_out[idx] = ws[TW_OFF + idx - MM - NN] / Sw;
}

extern "C" void kernel_launch(void* const* d_in, const int* in_sizes, int n_in,
                              void* d_out, int out_size, void* d_ws, size_t ws_size,
                              hipStream_t stream)
{
    const float* action = (const float*)d_in[0];
    const float* hidden = (const float*)d_in[1];
    const float* prev_r = (const float*)d_in[2];
    const float* prev_w = (const float*)d_in[3];
    const float* hprev  = (const float*)d_in[4];   // prev_controller_hidden
    const float* memory = (const float*)d_in[5];
    const float* W_ih   = (const float*)d_in[6];
    const float* W_hh   = (const float*)d_in[7];
    const float* b_ih   = (const float*)d_in[8];
    const float* b_hh   = (const float*)d_in[9];
    // d_in[10..19]: W_read/b_read/W_write/b_write/W_add/b_add/W_erase/b_erase/W_shift/b_shift
    // -> provably unused (softmax over size-1 axis == 1; conv scalar cancels; write discarded)
    const float* W_gamma = (const float*)d_in[20];
    const float* b_gamma = (const float*)d_in[21];
    const float* W_gate  = (const float*)d_in[22];
    const float* b_gate  = (const float*)d_in[23];

    float* ws  = (float*)d_ws;
    float* out = (float*)d_out;

    hipLaunchKernelGGL(k_gru_gates, dim3(3 * CC), dim3(256), 0, stream,
                       action, hidden, W_ih, W_hh, b_ih, b_hh, hprev, ws);
    hipLaunchKernelGGL(k_gru_combine, dim3(1), dim3(1024), 0, stream,
                       hprev, W_gate, b_gate, W_gamma, b_gamma, ws, out);
    hipLaunchKernelGGL(k_weights, dim3(NN / 256), dim3(256), 0, stream,
                       prev_r, prev_w, ws);
    hipLaunchKernelGGL(k_readvec, dim3(4, 256), dim3(256), 0, stream,
                       memory, ws);
    hipLaunchKernelGGL(k_finalize, dim3((MM + 2 * NN) / 256), dim3(256), 0, stream,
                       ws, out);
}

// Round 2
// 317.785 us; speedup vs baseline: 1.0371x; 1.0371x over previous
//
#include <hip/hip_runtime.h>
#include <math.h>

// Problem dims
#define AA 256
#define HH 1024
#define CC 1024
#define NN 8192
#define MM 4096

// ws layout (float offsets).
#define WS_G      0
#define WS_GAMMA  1
#define WS_SR     2
#define WS_SW     3
#define GI_OFF    4
#define GH_OFF    (GI_OFF + 3*CC)          // 3076
#define TR_OFF    (GH_OFF + 3*CC)          // 6148
#define TW_OFF    (TR_OFF + NN)            // 14340
#define P_OFF     (TW_OFF + NN)            // 22532; partials: 256 x 4096 floats = 4 MB

__device__ __forceinline__ float wave_reduce(float v) {
    #pragma unroll
    for (int o = 32; o > 0; o >>= 1) v += __shfl_down(v, o);
    return v;
}

// Kernel 1: gi[row] = dot(x, W_ih[row]) + b_ih; gh[row] = dot(h_prev, W_hh[row]) + b_hh.
// Wave-per-row: 768 blocks x 256 threads (4 waves = 4 rows/block). 9 independent
// float4 loads per lane -> deep MLP, shuffle-only reduce, no LDS.
__global__ __launch_bounds__(256) void k_gru_gates(
    const float* __restrict__ action, const float* __restrict__ hidden,
    const float* __restrict__ W_ih, const float* __restrict__ W_hh,
    const float* __restrict__ b_ih, const float* __restrict__ b_hh,
    const float* __restrict__ hprev, float* __restrict__ ws)
{
    const int t = threadIdx.x;
    const int wid = t >> 6, lane = t & 63;
    const int row = blockIdx.x * 4 + wid;

    const float4* __restrict__ Wih4 = (const float4*)W_ih + (size_t)row * 320; // 1280/4
    const float4* __restrict__ Whh4 = (const float4*)W_hh + (size_t)row * 256; // 1024/4
    const float4* __restrict__ act4 = (const float4*)action;  // 64 float4
    const float4* __restrict__ hid4 = (const float4*)hidden;  // 256 float4
    const float4* __restrict__ hp4  = (const float4*)hprev;   // 256 float4

    float4 a[5], b[4], xa[5], xb[4];
    #pragma unroll
    for (int j = 0; j < 5; ++j) a[j] = Wih4[lane + 64 * j];
    #pragma unroll
    for (int j = 0; j < 4; ++j) b[j] = Whh4[lane + 64 * j];
    xa[0] = act4[lane];
    #pragma unroll
    for (int j = 1; j < 5; ++j) xa[j] = hid4[lane + 64 * (j - 1)];
    #pragma unroll
    for (int j = 0; j < 4; ++j) xb[j] = hp4[lane + 64 * j];

    float si = 0.0f, sh = 0.0f;
    #pragma unroll
    for (int j = 0; j < 5; ++j)
        si += a[j].x * xa[j].x + a[j].y * xa[j].y + a[j].z * xa[j].z + a[j].w * xa[j].w;
    #pragma unroll
    for (int j = 0; j < 4; ++j)
        sh += b[j].x * xb[j].x + b[j].y * xb[j].y + b[j].z * xb[j].z + b[j].w * xb[j].w;

    si = wave_reduce(si);
    sh = wave_reduce(sh);
    if (lane == 0) {
        ws[GI_OFF + row] = si + b_ih[row];
        ws[GH_OFF + row] = sh + b_hh[row];
    }
}

// Kernel 2 (1 block, 1024 threads): GRU combine -> h; write hidden output;
// g = sigmoid(h.W_gate + b), gamma = softplus(h.W_gamma + b). Also zero S_r/S_w
// (ws is 0xAA-poisoned before every launch).
__global__ __launch_bounds__(1024) void k_gru_combine(
    const float* __restrict__ hprev,
    const float* __restrict__ W_gate, const float* __restrict__ b_gate,
    const float* __restrict__ W_gamma, const float* __restrict__ b_gamma,
    float* __restrict__ ws, float* __restrict__ d_out)
{
    const int c = threadIdx.x;
    if (c == 1) ws[WS_SR] = 0.0f;
    if (c == 2) ws[WS_SW] = 0.0f;
    const float* gi = ws + GI_OFF;
    const float* gh = ws + GH_OFF;
    const float r = 1.0f / (1.0f + expf(-(gi[c] + gh[c])));
    const float z = 1.0f / (1.0f + expf(-(gi[CC + c] + gh[CC + c])));
    const float n = tanhf(gi[2 * CC + c] + r * gh[2 * CC + c]);
    const float h = (1.0f - z) * n + z * hprev[c];
    d_out[MM + 2 * NN + c] = h;   // new_controller_hidden section

    float vg = h * W_gate[c];
    float vm = h * W_gamma[c];
    vg = wave_reduce(vg);
    vm = wave_reduce(vm);
    __shared__ float rg[16], rm[16];
    const int wid = c >> 6;
    if ((c & 63) == 0) { rg[wid] = vg; rm[wid] = vm; }
    __syncthreads();
    if (c == 0) {
        float sg = 0.0f, sm = 0.0f;
        #pragma unroll
        for (int i = 0; i < 16; ++i) { sg += rg[i]; sm += rm[i]; }
        sg += b_gate[0];
        sm += b_gamma[0];
        ws[WS_G] = 1.0f / (1.0f + expf(-sg));
        ws[WS_GAMMA] = (sm > 20.0f) ? sm : log1pf(expf(sm));
    }
}

// Kernel 3: the 128 MB pass. Grid (4, 256), block 256. Block (bx,by) covers
// float4-cols [bx*256, bx*256+256) x rows [by*32, by*32+32). Each thread: one
// float4 column, 32 rows, 8 independent loads in flight (Little's law fix).
// Cosine-sim weights are identically 1.0 (softmax over size-1 axis) and the
// circular-conv scalar cancels in sharpen, so t_i = (g+(1-g)*prev_i)^gamma is
// computed inline (32 powf per block). bx==0 blocks also emit t_r/t_w arrays
// and the S_r/S_w atomic partial sums (merging the old k_weights stage).
// Partials stored per (by, col) -- no global atomics on the hot path.
__global__ __launch_bounds__(256) void k_readvec(
    const float* __restrict__ memory,
    const float* __restrict__ prev_r, const float* __restrict__ prev_w,
    float* __restrict__ ws)
{
    __shared__ float tch[32];
    const int t = threadIdx.x;
    const int bx = blockIdx.x;      // 0..3
    const int by = blockIdx.y;      // 0..255
    const int row0 = by * 32;

    if (t < 32) {
        const float g = ws[WS_G];
        const float gamma = ws[WS_GAMMA];
        const float tr = powf(g + (1.0f - g) * prev_r[row0 + t], gamma);
        tch[t] = tr;
        if (bx == 0) {
            const float tw = powf(g + (1.0f - g) * prev_w[row0 + t], gamma);
            ws[TR_OFF + row0 + t] = tr;
            ws[TW_OFF + row0 + t] = tw;
            float sr = tr, sw = tw;
            #pragma unroll
            for (int o = 16; o > 0; o >>= 1) {
                sr += __shfl_down(sr, o);
                sw += __shfl_down(sw, o);
            }
            if (t == 0) { atomicAdd(&ws[WS_SR], sr); atomicAdd(&ws[WS_SW], sw); }
        }
    }
    __syncthreads();

    const int c4 = bx * 256 + t;    // float4 column, 0..1023
    const float4* __restrict__ mem4 = (const float4*)memory + (size_t)row0 * 1024 + c4;
    float ax = 0.0f, ay = 0.0f, az = 0.0f, aw = 0.0f;
    #pragma unroll
    for (int grp = 0; grp < 4; ++grp) {
        float4 m[8];
        #pragma unroll
        for (int j = 0; j < 8; ++j)
            m[j] = mem4[(size_t)(grp * 8 + j) * 1024];
        #pragma unroll
        for (int j = 0; j < 8; ++j) {
            const float w = tch[grp * 8 + j];
            ax += w * m[j].x; ay += w * m[j].y; az += w * m[j].z; aw += w * m[j].w;
        }
    }
    float4 acc; acc.x = ax; acc.y = ay; acc.z = az; acc.w = aw;
    ((float4*)(ws + P_OFF))[(size_t)by * 1024 + c4] = acc;
}

// Kernel 4: finalize. Blocks 0..15: read_vector[col] = sum_yb P[yb][col] / S_r
// (coalesced across threads at every yb iteration, 4-way accumulator ILP).
// Blocks 16..79: weight outputs t/S.
__global__ __launch_bounds__(256) void k_finalize(
    const float* __restrict__ ws, float* __restrict__ d_out)
{
    const int t = threadIdx.x, b = blockIdx.x;
    if (b < 16) {
        const int col = b * 256 + t;
        const float* __restrict__ P = ws + P_OFF;
        float s0 = 0.0f, s1 = 0.0f, s2 = 0.0f, s3 = 0.0f;
        #pragma unroll 8
        for (int yb = 0; yb < 256; yb += 4) {
            s0 += P[(size_t)(yb + 0) * 4096 + col];
            s1 += P[(size_t)(yb + 1) * 4096 + col];
            s2 += P[(size_t)(yb + 2) * 4096 + col];
            s3 += P[(size_t)(yb + 3) * 4096 + col];
        }
        d_out[col] = (s0 + s1 + s2 + s3) / ws[WS_SR];
    } else {
        const int idx = (b - 16) * 256 + t;   // 0..16383
        d_out[MM + idx] = (idx < NN) ? ws[TR_OFF + idx] / ws[WS_SR]
                                     : ws[TW_OFF + idx - NN] / ws[WS_SW];
    }
}

extern "C" void kernel_launch(void* const* d_in, const int* in_sizes, int n_in,
                              void* d_out, int out_size, void* d_ws, size_t ws_size,
                              hipStream_t stream)
{
    const float* action = (const float*)d_in[0];
    const float* hidden = (const float*)d_in[1];
    const float* prev_r = (const float*)d_in[2];
    const float* prev_w = (const float*)d_in[3];
    const float* hprev  = (const float*)d_in[4];   // prev_controller_hidden
    const float* memory = (const float*)d_in[5];
    const float* W_ih   = (const float*)d_in[6];
    const float* W_hh   = (const float*)d_in[7];
    const float* b_ih   = (const float*)d_in[8];
    const float* b_hh   = (const float*)d_in[9];
    // d_in[10..19]: W_read/b_read/W_write/b_write/W_add/b_add/W_erase/b_erase/W_shift/b_shift
    // -> provably unused (softmax over size-1 axis == 1; conv scalar cancels; write discarded)
    const float* W_gamma = (const float*)d_in[20];
    const float* b_gamma = (const float*)d_in[21];
    const float* W_gate  = (const float*)d_in[22];
    const float* b_gate  = (const float*)d_in[23];

    float* ws  = (float*)d_ws;
    float* out = (float*)d_out;

    hipLaunchKernelGGL(k_gru_gates, dim3(3 * CC / 4), dim3(256), 0, stream,
                       action, hidden, W_ih, W_hh, b_ih, b_hh, hprev, ws);
    hipLaunchKernelGGL(k_gru_combine, dim3(1), dim3(1024), 0, stream,
                       hprev, W_gate, b_gate, W_gamma, b_gamma, ws, out);
    hipLaunchKernelGGL(k_readvec, dim3(4, 256), dim3(256), 0, stream,
                       memory, prev_r, prev_w, ws);
    hipLaunchKernelGGL(k_finalize, dim3(80), dim3(256), 0, stream,
                       ws, out);
}